// Round 5
// baseline (285.446 us; speedup 1.0000x reference)
//
#include <hip/hip_runtime.h>
#include <cstdint>

#define BN 9216      // N = H*W = 96*96
#define NB 2         // batch
#define CIN 64       // C
#define DI 32        // inter
#define LOG2E 1.4426950408889634f

typedef __attribute__((ext_vector_type(4))) float f32x4;
typedef __attribute__((ext_vector_type(8))) __bf16 bf16x8;
typedef __attribute__((ext_vector_type(4))) __bf16 bf16x4;
typedef __attribute__((ext_vector_type(4))) short s16x4;
typedef __attribute__((ext_vector_type(4))) unsigned int u32x4;

// fp32 -> bf16 bits, round-to-nearest-even
__device__ __forceinline__ unsigned short f2bf(float f) {
    unsigned int u = __builtin_bit_cast(unsigned int, f);
    u += 0x7FFFu + ((u >> 16) & 1u);
    return (unsigned short)(u >> 16);
}
__device__ __forceinline__ unsigned int packbf(float lo, float hi) {
    return (unsigned int)f2bf(lo) | ((unsigned int)f2bf(hi) << 16);
}

// hardware exp2 (v_exp_f32 IS 2^x); exp2(-inf)=0 handles first-tile corr
__device__ __forceinline__ float exp2_hw(float x) {
    float r;
    asm("v_exp_f32 %0, %1" : "=v"(r) : "v"(x));
    return r;
}

// 16x16x16 bf16 MFMA (k = 4*(lane>>4)+j matches QK^T output rows directly)
__device__ __forceinline__ f32x4 mfma16(bf16x4 a, bf16x4 b, f32x4 c) {
#if __has_builtin(__builtin_amdgcn_mfma_f32_16x16x16bf16_1k)
    return __builtin_amdgcn_mfma_f32_16x16x16bf16_1k(
        __builtin_bit_cast(s16x4, a), __builtin_bit_cast(s16x4, b), c, 0, 0, 0);
#elif __has_builtin(__builtin_amdgcn_mfma_f32_16x16x16_bf16)
    return __builtin_amdgcn_mfma_f32_16x16x16_bf16(a, b, c, 0, 0, 0);
#else
    f32x4 d;
    asm("v_mfma_f32_16x16x16_bf16 %0, %1, %2, %3"
        : "=v"(d) : "v"(a), "v"(b), "v"(c));
    return d;
#endif
}

// ---------------------------------------------------------------------------
// Kernel 1: fused conv1x1 for phi/theta/g, o-split x4 for occupancy.
// grid = (BN/64, 12, NB); block = 64. blockIdx.y: which = y>>2, ogroup = y&3.
// Each thread: one n, 8 output channels, all 64 input channels.
//   qT/kT: [B][N][32] bf16 (phi scaled by LOG2E); v: [B][32][N] bf16
// ---------------------------------------------------------------------------
__global__ __launch_bounds__(64) void qkv_kernel(
    const float* __restrict__ x,
    const float* __restrict__ g_w, const float* __restrict__ g_b,
    const float* __restrict__ th_w, const float* __restrict__ th_b,
    const float* __restrict__ ph_w, const float* __restrict__ ph_b,
    unsigned short* __restrict__ qT, unsigned short* __restrict__ kT,
    unsigned short* __restrict__ vv)
{
    __shared__ float wsh[8 * CIN];
    const int which = blockIdx.y >> 2;    // 0 = phi->qT, 1 = theta->kT, 2 = g->v
    const int og    = blockIdx.y & 3;     // output-channel group (8 each)
    const int b = blockIdx.z;
    const int tid = threadIdx.x;
    const float* w    = (which == 0) ? ph_w : (which == 1) ? th_w : g_w;
    const float* bias = (which == 0) ? ph_b : (which == 1) ? th_b : g_b;
    const float scale = (which == 0) ? LOG2E : 1.0f;
    for (int i = tid; i < 8 * CIN; i += 64)
        wsh[i] = w[(size_t)(og * 8 + i / CIN) * CIN + (i % CIN)] * scale;
    __syncthreads();

    const int n = blockIdx.x * 64 + tid;
    const float* xp = x + (size_t)b * CIN * BN + n;

    float acc[8];
#pragma unroll
    for (int o = 0; o < 8; ++o) acc[o] = bias[og * 8 + o] * scale;
    for (int c0 = 0; c0 < CIN; c0 += 16) {     // 16 loads in flight per batch
        float xv[16];
#pragma unroll
        for (int u = 0; u < 16; ++u) xv[u] = xp[(size_t)(c0 + u) * BN];
#pragma unroll
        for (int u = 0; u < 16; ++u)
#pragma unroll
            for (int o = 0; o < 8; ++o) acc[o] += wsh[o * CIN + c0 + u] * xv[u];
    }

    if (which == 2) {
        unsigned short* vp = vv + (size_t)b * DI * BN + n;
#pragma unroll
        for (int o = 0; o < 8; ++o) vp[(size_t)(og * 8 + o) * BN] = f2bf(acc[o]);
    } else {
        unsigned short* outp = ((which == 0) ? qT : kT)
                               + ((size_t)b * BN + n) * DI + og * 8;
        u32x4 t = {packbf(acc[0], acc[1]), packbf(acc[2], acc[3]),
                   packbf(acc[4], acc[5]), packbf(acc[6], acc[7])};
        *(u32x4*)outp = t;
    }
}

// ---------------------------------------------------------------------------
// Kernel 2: flash attention. Block = 512 threads = 8 waves, 16 queries/block.
// Each wave: 8-way m-split (m0 = w*32 step 256). Swapped QK^T: lane holds
// S[m0+4h+t][q] -> feeds PV mfma16 B-operand (k=4h+j) with zero repack.
// Online softmax in log2 domain, deferred-max THR=8. LDS combine of 8
// partial (m,l,acc) once per block.
// ---------------------------------------------------------------------------
__global__ __launch_bounds__(512) void attn_kernel(
    const unsigned short* __restrict__ qT, const unsigned short* __restrict__ kT,
    const unsigned short* __restrict__ vv, float* __restrict__ yT)
{
    __shared__ float red_m[8][16];
    __shared__ float red_l[8][16];
    __shared__ float red_acc[8][512];   // [wave][i*16+q]

    const int b = blockIdx.y;
    const int n0 = blockIdx.x * 16;     // 16 queries per block
    const int tid = threadIdx.x;
    const int w = tid >> 6;
    const int lane = tid & 63;
    const int h = lane >> 4;
    const int q = lane & 15;

    const unsigned short* qTb = qT + (size_t)b * BN * DI;
    const unsigned short* kTb = kT + (size_t)b * BN * DI;
    const unsigned short* vb  = vv + (size_t)b * DI * BN;

    bf16x8 qf = *(const bf16x8*)(qTb + ((size_t)(n0 + q)) * DI + 8 * h);
    const f32x4 zero = {0.f, 0.f, 0.f, 0.f};
    f32x4 a0 = zero, a1 = zero;         // yT rows 4h+t and 16+4h+t, col n0+q
    float m = -INFINITY, l = 0.f;

    const unsigned short* vrow0 = vb + (size_t)q * BN;
    const unsigned short* vrow1 = vb + (size_t)(16 + q) * BN;

    for (int m0 = w * 32; m0 < BN; m0 += 256) {
        bf16x8 k0 = *(const bf16x8*)(kTb + ((size_t)(m0 + q)) * DI + 8 * h);
        bf16x8 k1 = *(const bf16x8*)(kTb + ((size_t)(m0 + 16 + q)) * DI + 8 * h);
        bf16x4 v00 = *(const bf16x4*)(vrow0 + m0 + 4 * h);
        bf16x4 v01 = *(const bf16x4*)(vrow0 + m0 + 16 + 4 * h);
        bf16x4 v10 = *(const bf16x4*)(vrow1 + m0 + 4 * h);
        bf16x4 v11 = *(const bf16x4*)(vrow1 + m0 + 16 + 4 * h);
        f32x4 s0 = __builtin_amdgcn_mfma_f32_16x16x32_bf16(k0, qf, zero, 0, 0, 0);
        f32x4 s1 = __builtin_amdgcn_mfma_f32_16x16x32_bf16(k1, qf, zero, 0, 0, 0);

        float tmax = fmaxf(fmaxf(fmaxf(s0[0], s0[1]), fmaxf(s0[2], s0[3])),
                           fmaxf(fmaxf(s1[0], s1[1]), fmaxf(s1[2], s1[3])));
        tmax = fmaxf(tmax, __shfl_xor(tmax, 16, 64));
        tmax = fmaxf(tmax, __shfl_xor(tmax, 32, 64));
        if (__any(tmax > m + 8.0f)) {              // deferred-max rescale
            float mnew = fmaxf(m, tmax);
            float corr = exp2_hw(m - mnew);
            l *= corr;
#pragma unroll
            for (int t = 0; t < 4; ++t) { a0[t] *= corr; a1[t] *= corr; }
            m = mnew;
        }
        float p0 = exp2_hw(s0[0] - m), p1 = exp2_hw(s0[1] - m);
        float p2 = exp2_hw(s0[2] - m), p3 = exp2_hw(s0[3] - m);
        float p4 = exp2_hw(s1[0] - m), p5 = exp2_hw(s1[1] - m);
        float p6 = exp2_hw(s1[2] - m), p7 = exp2_hw(s1[3] - m);
        l += ((p0 + p1) + (p2 + p3)) + ((p4 + p5) + (p6 + p7));
        bf16x4 pf0 = {(__bf16)p0, (__bf16)p1, (__bf16)p2, (__bf16)p3};
        bf16x4 pf1 = {(__bf16)p4, (__bf16)p5, (__bf16)p6, (__bf16)p7};
        a0 = mfma16(v00, pf0, a0);
        a0 = mfma16(v01, pf1, a0);
        a1 = mfma16(v10, pf0, a1);
        a1 = mfma16(v11, pf1, a1);
    }

    // per-lane partial l -> per-q partial (sum over h-groups)
    l += __shfl_xor(l, 16, 64);
    l += __shfl_xor(l, 32, 64);

    if (lane < 16) { red_m[w][lane] = m; red_l[w][lane] = l; }
    __syncthreads();

    // each wave rescales its partial acc to the block-global max, parks in LDS
    {
        float M = red_m[0][q];
#pragma unroll
        for (int w2 = 1; w2 < 8; ++w2) M = fmaxf(M, red_m[w2][q]);
        float sc = exp2_hw(m - M);
#pragma unroll
        for (int t = 0; t < 4; ++t) {
            red_acc[w][(4 * h + t) * 16 + q]      = a0[t] * sc;
            red_acc[w][(16 + 4 * h + t) * 16 + q] = a1[t] * sc;
        }
    }
    __syncthreads();

    // final: thread tid owns element (i = tid>>4, q2 = tid&15)
    {
        const int i = tid >> 4, q2 = tid & 15;
        float M = red_m[0][q2];
#pragma unroll
        for (int w2 = 1; w2 < 8; ++w2) M = fmaxf(M, red_m[w2][q2]);
        float L = 0.f, y = 0.f;
#pragma unroll
        for (int w2 = 0; w2 < 8; ++w2) {
            L += exp2_hw(red_m[w2][q2] - M) * red_l[w2][q2];
            y += red_acc[w2][i * 16 + q2];
        }
        yT[(size_t)b * DI * BN + (size_t)i * BN + n0 + q2] = y / L;
    }
}

// ---------------------------------------------------------------------------
// Kernel 3: out[b][o][n] = sum_i W_w[o][i]*yT[b][i][n] + W_b[o] + x[b][o][n]
// o-split x8 for occupancy: grid = (BN/64, 8, NB); block = 64.
// Each thread: one n, 8 output channels, all 32 inner channels.
// ---------------------------------------------------------------------------
__global__ __launch_bounds__(64) void outconv_kernel(
    const float* __restrict__ yT, const float* __restrict__ Ww,
    const float* __restrict__ Wb, const float* __restrict__ x,
    float* __restrict__ out)
{
    __shared__ float wsh[8 * DI];
    const int b = blockIdx.z;
    const int og = blockIdx.y;            // 8 groups of 8 output channels
    const int tid = threadIdx.x;
    for (int i = tid; i < 8 * DI; i += 64)
        wsh[i] = Ww[(size_t)(og * 8 + i / DI) * DI + (i % DI)];
    __syncthreads();

    const int n = blockIdx.x * 64 + tid;
    const float* yp = yT + (size_t)b * DI * BN + n;
    const float* xp = x + ((size_t)b * CIN + og * 8) * BN + n;

    float xr[8];                          // hoist residual loads early
#pragma unroll
    for (int o = 0; o < 8; ++o) xr[o] = xp[(size_t)o * BN];

    float acc[8];
#pragma unroll
    for (int o = 0; o < 8; ++o) acc[o] = Wb[og * 8 + o];
    for (int i0 = 0; i0 < DI; i0 += 16) {
        float yv[16];
#pragma unroll
        for (int u = 0; u < 16; ++u) yv[u] = yp[(size_t)(i0 + u) * BN];
#pragma unroll
        for (int u = 0; u < 16; ++u)
#pragma unroll
            for (int o = 0; o < 8; ++o) acc[o] += wsh[o * DI + i0 + u] * yv[u];
    }

    float* op = out + ((size_t)b * CIN + og * 8) * BN + n;
#pragma unroll
    for (int o = 0; o < 8; ++o) op[(size_t)o * BN] = acc[o] + xr[o];
}

// ---------------------------------------------------------------------------
extern "C" void kernel_launch(void* const* d_in, const int* in_sizes, int n_in,
                              void* d_out, int out_size, void* d_ws, size_t ws_size,
                              hipStream_t stream)
{
    const float* x    = (const float*)d_in[0];
    const float* g_w  = (const float*)d_in[1];
    const float* g_b  = (const float*)d_in[2];
    const float* th_w = (const float*)d_in[3];
    const float* th_b = (const float*)d_in[4];
    const float* ph_w = (const float*)d_in[5];
    const float* ph_b = (const float*)d_in[6];
    const float* W_w  = (const float*)d_in[7];
    const float* W_b  = (const float*)d_in[8];
    float* out = (float*)d_out;

    char* ws = (char*)d_ws;
    unsigned short* qT = (unsigned short*)(ws);                 // 1179648 B
    unsigned short* kT = (unsigned short*)(ws + 1179648);       // 1179648 B
    unsigned short* vv = (unsigned short*)(ws + 2359296);       // 1179648 B
    float*          yT = (float*)        (ws + 3538944);        // 2359296 B

    dim3 g1(BN / 64, 12, NB);
    qkv_kernel<<<g1, 64, 0, stream>>>(x, g_w, g_b, th_w, th_b, ph_w, ph_b,
                                      qT, kT, vv);
    dim3 g2(BN / 16, NB);
    attn_kernel<<<g2, 512, 0, stream>>>(qT, kT, vv, yT);
    dim3 g3(BN / 64, 8, NB);
    outconv_kernel<<<g3, 64, 0, stream>>>(yT, W_w, W_b, x, out);
}

// Round 9
// 150.697 us; speedup vs baseline: 1.8942x; 1.8942x over previous
//
#include <hip/hip_runtime.h>
#include <cstdint>

#define BN 9216      // N = H*W = 96*96
#define NB 2         // batch
#define CIN 64       // C
#define DI 32        // inter
#define MC 8         // m-chunks (cross-block m-split)
#define NCHUNK 288   // BN/32 query chunks
#define LOG2E 1.4426950408889634f

typedef __attribute__((ext_vector_type(4))) float f32x4;
typedef __attribute__((ext_vector_type(8))) __bf16 bf16x8;
typedef __attribute__((ext_vector_type(4))) __bf16 bf16x4;
typedef __attribute__((ext_vector_type(4))) short s16x4;
typedef __attribute__((ext_vector_type(4))) unsigned int u32x4;

// fp32 -> bf16 bits, round-to-nearest-even
__device__ __forceinline__ unsigned short f2bf(float f) {
    unsigned int u = __builtin_bit_cast(unsigned int, f);
    u += 0x7FFFu + ((u >> 16) & 1u);
    return (unsigned short)(u >> 16);
}
__device__ __forceinline__ unsigned int packbf(float lo, float hi) {
    return (unsigned int)f2bf(lo) | ((unsigned int)f2bf(hi) << 16);
}

// hardware exp2 (v_exp_f32 IS 2^x); exp2(-inf)=0 handles first-tile corr
__device__ __forceinline__ float exp2_hw(float x) {
    float r;
    asm("v_exp_f32 %0, %1" : "=v"(r) : "v"(x));
    return r;
}

// 16x16x16 bf16 MFMA (k = 4*(lane>>4)+j matches QK^T output rows directly)
__device__ __forceinline__ f32x4 mfma16(bf16x4 a, bf16x4 b, f32x4 c) {
#if __has_builtin(__builtin_amdgcn_mfma_f32_16x16x16bf16_1k)
    return __builtin_amdgcn_mfma_f32_16x16x16bf16_1k(
        __builtin_bit_cast(s16x4, a), __builtin_bit_cast(s16x4, b), c, 0, 0, 0);
#elif __has_builtin(__builtin_amdgcn_mfma_f32_16x16x16_bf16)
    return __builtin_amdgcn_mfma_f32_16x16x16_bf16(a, b, c, 0, 0, 0);
#else
    f32x4 d;
    asm("v_mfma_f32_16x16x16_bf16 %0, %1, %2, %3"
        : "=v"(d) : "v"(a), "v"(b), "v"(c));
    return d;
#endif
}

// ---------------------------------------------------------------------------
// Kernel 1: fused conv1x1 for phi/theta/g, o-split x4 for occupancy.
// grid = (BN/64, 12, NB); block = 64. blockIdx.y: which = y>>2, ogroup = y&3.
//   qT/kT: [B][N][32] bf16 (phi scaled by LOG2E)
//   vv   : [B][32][N] bf16, with each 32-m chunk PERMUTED as
//          pos = (r>>2 &3)*8 + (r>>4)*4 + (r&3) so attn's PV fragments
//          (m0+4h..+3, m0+16+4h..+3) form one contiguous 16B load.
// ---------------------------------------------------------------------------
__global__ __launch_bounds__(64) void qkv_kernel(
    const float* __restrict__ x,
    const float* __restrict__ g_w, const float* __restrict__ g_b,
    const float* __restrict__ th_w, const float* __restrict__ th_b,
    const float* __restrict__ ph_w, const float* __restrict__ ph_b,
    unsigned short* __restrict__ qT, unsigned short* __restrict__ kT,
    unsigned short* __restrict__ vv)
{
    __shared__ float wsh[8 * CIN];
    const int which = blockIdx.y >> 2;    // 0 = phi->qT, 1 = theta->kT, 2 = g->v
    const int og    = blockIdx.y & 3;     // output-channel group (8 each)
    const int b = blockIdx.z;
    const int tid = threadIdx.x;
    const float* w    = (which == 0) ? ph_w : (which == 1) ? th_w : g_w;
    const float* bias = (which == 0) ? ph_b : (which == 1) ? th_b : g_b;
    const float scale = (which == 0) ? LOG2E : 1.0f;
    for (int i = tid; i < 8 * CIN; i += 64)
        wsh[i] = w[(size_t)(og * 8 + i / CIN) * CIN + (i % CIN)] * scale;
    __syncthreads();

    const int n = blockIdx.x * 64 + tid;
    const float* xp = x + (size_t)b * CIN * BN + n;

    float acc[8];
#pragma unroll
    for (int o = 0; o < 8; ++o) acc[o] = bias[og * 8 + o] * scale;
    for (int c0 = 0; c0 < CIN; c0 += 16) {     // 16 loads in flight per batch
        float xv[16];
#pragma unroll
        for (int u = 0; u < 16; ++u) xv[u] = xp[(size_t)(c0 + u) * BN];
#pragma unroll
        for (int u = 0; u < 16; ++u)
#pragma unroll
            for (int o = 0; o < 8; ++o) acc[o] += wsh[o * CIN + c0 + u] * xv[u];
    }

    if (which == 2) {
        const int r = n & 31;
        const int pos = (n & ~31) + ((r >> 2) & 3) * 8 + (r >> 4) * 4 + (r & 3);
        unsigned short* vp = vv + (size_t)b * DI * BN + pos;
#pragma unroll
        for (int o = 0; o < 8; ++o) vp[(size_t)(og * 8 + o) * BN] = f2bf(acc[o]);
    } else {
        unsigned short* outp = ((which == 0) ? qT : kT)
                               + ((size_t)b * BN + n) * DI + og * 8;
        u32x4 t = {packbf(acc[0], acc[1]), packbf(acc[2], acc[3]),
                   packbf(acc[4], acc[5]), packbf(acc[6], acc[7])};
        *(u32x4*)outp = t;
    }
}

// ---------------------------------------------------------------------------
// Kernel 2: flash-attention partial. grid = (NCHUNK, MC, NB), block = 256.
// Block (nc, mc, b): queries n0..n0+32, m-range mc*1152..+1152.
// 4 waves split m (w*32, step 128, 9 iters); each wave handles BOTH n-tiles
// sharing k/v loads (ILP=2). Swapped QK^T: lane holds S[m0+4h+t][q] which
// feeds PV mfma16 B-operand (k=4h+j) with zero repack. V is chunk-permuted
// so each PV A-fragment pair is one 16B load. Online softmax in log2
// domain, deferred-max THR=8. LDS combine of the 4 waves, then write
// partial (M, L, acc[32i][32n]) to workspace.
// ---------------------------------------------------------------------------
__global__ __launch_bounds__(256) void attn_partial(
    const unsigned short* __restrict__ qT, const unsigned short* __restrict__ kT,
    const unsigned short* __restrict__ vv,
    float* __restrict__ pacc, float* __restrict__ pml)
{
    __shared__ float red_m[4][2][16];
    __shared__ float red_l[4][2][16];
    __shared__ float red_acc[4][2][512];   // [wave][tile][i*16+q]

    const int b  = blockIdx.z;
    const int mc = blockIdx.y;
    const int nc = blockIdx.x;
    const int n0 = nc * 32;
    const int tid = threadIdx.x;
    const int w = tid >> 6;
    const int lane = tid & 63;
    const int h = lane >> 4;
    const int q = lane & 15;

    const unsigned short* qTb = qT + (size_t)b * BN * DI;
    const unsigned short* kTb = kT + (size_t)b * BN * DI;
    const unsigned short* vb  = vv + (size_t)b * DI * BN;

    bf16x8 qfA = *(const bf16x8*)(qTb + ((size_t)(n0 + q)) * DI + 8 * h);
    bf16x8 qfB = *(const bf16x8*)(qTb + ((size_t)(n0 + 16 + q)) * DI + 8 * h);
    const f32x4 zero = {0.f, 0.f, 0.f, 0.f};
    f32x4 a0A = zero, a1A = zero, a0B = zero, a1B = zero;
    float mA = -INFINITY, lA = 0.f;
    float mB = -INFINITY, lB = 0.f;

    const unsigned short* vrow0 = vb + (size_t)q * BN;
    const unsigned short* vrow1 = vb + (size_t)(16 + q) * BN;

    int m0 = mc * 1152 + w * 32;
#pragma unroll 1
    for (int it = 0; it < 9; ++it, m0 += 128) {
        bf16x8 k0 = *(const bf16x8*)(kTb + ((size_t)(m0 + q)) * DI + 8 * h);
        bf16x8 k1 = *(const bf16x8*)(kTb + ((size_t)(m0 + 16 + q)) * DI + 8 * h);
        bf16x8 vr0 = *(const bf16x8*)(vrow0 + m0 + 8 * h);  // permuted chunk
        bf16x8 vr1 = *(const bf16x8*)(vrow1 + m0 + 8 * h);
        f32x4 s0A = __builtin_amdgcn_mfma_f32_16x16x32_bf16(k0, qfA, zero, 0, 0, 0);
        f32x4 s1A = __builtin_amdgcn_mfma_f32_16x16x32_bf16(k1, qfA, zero, 0, 0, 0);
        f32x4 s0B = __builtin_amdgcn_mfma_f32_16x16x32_bf16(k0, qfB, zero, 0, 0, 0);
        f32x4 s1B = __builtin_amdgcn_mfma_f32_16x16x32_bf16(k1, qfB, zero, 0, 0, 0);

        bf16x4 vlo0 = __builtin_shufflevector(vr0, vr0, 0, 1, 2, 3);
        bf16x4 vhi0 = __builtin_shufflevector(vr0, vr0, 4, 5, 6, 7);
        bf16x4 vlo1 = __builtin_shufflevector(vr1, vr1, 0, 1, 2, 3);
        bf16x4 vhi1 = __builtin_shufflevector(vr1, vr1, 4, 5, 6, 7);

        // ---- tile A ----
        {
            float tmax = fmaxf(fmaxf(fmaxf(s0A[0], s0A[1]), fmaxf(s0A[2], s0A[3])),
                               fmaxf(fmaxf(s1A[0], s1A[1]), fmaxf(s1A[2], s1A[3])));
            tmax = fmaxf(tmax, __shfl_xor(tmax, 16, 64));
            tmax = fmaxf(tmax, __shfl_xor(tmax, 32, 64));
            if (__any(tmax > mA + 8.0f)) {            // deferred-max rescale
                float mnew = fmaxf(mA, tmax);
                float corr = exp2_hw(mA - mnew);
                lA *= corr;
#pragma unroll
                for (int t = 0; t < 4; ++t) { a0A[t] *= corr; a1A[t] *= corr; }
                mA = mnew;
            }
            float p0 = exp2_hw(s0A[0] - mA), p1 = exp2_hw(s0A[1] - mA);
            float p2 = exp2_hw(s0A[2] - mA), p3 = exp2_hw(s0A[3] - mA);
            float p4 = exp2_hw(s1A[0] - mA), p5 = exp2_hw(s1A[1] - mA);
            float p6 = exp2_hw(s1A[2] - mA), p7 = exp2_hw(s1A[3] - mA);
            lA += ((p0 + p1) + (p2 + p3)) + ((p4 + p5) + (p6 + p7));
            bf16x4 pf0 = {(__bf16)p0, (__bf16)p1, (__bf16)p2, (__bf16)p3};
            bf16x4 pf1 = {(__bf16)p4, (__bf16)p5, (__bf16)p6, (__bf16)p7};
            a0A = mfma16(vlo0, pf0, a0A);
            a0A = mfma16(vhi0, pf1, a0A);
            a1A = mfma16(vlo1, pf0, a1A);
            a1A = mfma16(vhi1, pf1, a1A);
        }
        // ---- tile B ----
        {
            float tmax = fmaxf(fmaxf(fmaxf(s0B[0], s0B[1]), fmaxf(s0B[2], s0B[3])),
                               fmaxf(fmaxf(s1B[0], s1B[1]), fmaxf(s1B[2], s1B[3])));
            tmax = fmaxf(tmax, __shfl_xor(tmax, 16, 64));
            tmax = fmaxf(tmax, __shfl_xor(tmax, 32, 64));
            if (__any(tmax > mB + 8.0f)) {
                float mnew = fmaxf(mB, tmax);
                float corr = exp2_hw(mB - mnew);
                lB *= corr;
#pragma unroll
                for (int t = 0; t < 4; ++t) { a0B[t] *= corr; a1B[t] *= corr; }
                mB = mnew;
            }
            float p0 = exp2_hw(s0B[0] - mB), p1 = exp2_hw(s0B[1] - mB);
            float p2 = exp2_hw(s0B[2] - mB), p3 = exp2_hw(s0B[3] - mB);
            float p4 = exp2_hw(s1B[0] - mB), p5 = exp2_hw(s1B[1] - mB);
            float p6 = exp2_hw(s1B[2] - mB), p7 = exp2_hw(s1B[3] - mB);
            lB += ((p0 + p1) + (p2 + p3)) + ((p4 + p5) + (p6 + p7));
            bf16x4 pf0 = {(__bf16)p0, (__bf16)p1, (__bf16)p2, (__bf16)p3};
            bf16x4 pf1 = {(__bf16)p4, (__bf16)p5, (__bf16)p6, (__bf16)p7};
            a0B = mfma16(vlo0, pf0, a0B);
            a0B = mfma16(vhi0, pf1, a0B);
            a1B = mfma16(vlo1, pf0, a1B);
            a1B = mfma16(vhi1, pf1, a1B);
        }
    }

    // per-lane partial l -> per-q partial (sum over h-groups)
    lA += __shfl_xor(lA, 16, 64); lA += __shfl_xor(lA, 32, 64);
    lB += __shfl_xor(lB, 16, 64); lB += __shfl_xor(lB, 32, 64);

    if (lane < 16) {
        red_m[w][0][lane] = mA; red_l[w][0][lane] = lA;
        red_m[w][1][lane] = mB; red_l[w][1][lane] = lB;
    }
    __syncthreads();

    // each wave rescales its partial acc to the block-global max, parks in LDS
    {
        float MA = red_m[0][0][q], MB = red_m[0][1][q];
#pragma unroll
        for (int w2 = 1; w2 < 4; ++w2) {
            MA = fmaxf(MA, red_m[w2][0][q]);
            MB = fmaxf(MB, red_m[w2][1][q]);
        }
        float scA = exp2_hw(mA - MA), scB = exp2_hw(mB - MB);
#pragma unroll
        for (int t = 0; t < 4; ++t) {
            red_acc[w][0][(4 * h + t) * 16 + q]      = a0A[t] * scA;
            red_acc[w][0][(16 + 4 * h + t) * 16 + q] = a1A[t] * scA;
            red_acc[w][1][(4 * h + t) * 16 + q]      = a0B[t] * scB;
            red_acc[w][1][(16 + 4 * h + t) * 16 + q] = a1B[t] * scB;
        }
    }
    __syncthreads();

    // write partial acc: thread t -> n' = t&31 (tile tt, col qq), 4 i's
    {
        const int np = tid & 31;
        const int ig = tid >> 5;
        const int tt = np >> 4, qq = np & 15;
        const size_t pbase = (((size_t)b * MC + mc) * NCHUNK + nc) * 1024;
#pragma unroll
        for (int ii = 0; ii < 4; ++ii) {
            const int i = ig * 4 + ii;
            float ysum = red_acc[0][tt][i * 16 + qq] + red_acc[1][tt][i * 16 + qq]
                       + red_acc[2][tt][i * 16 + qq] + red_acc[3][tt][i * 16 + qq];
            pacc[pbase + (size_t)i * 32 + np] = ysum;
        }
        if (tid < 32) {
            float M = red_m[0][tt][qq];
#pragma unroll
            for (int w2 = 1; w2 < 4; ++w2) M = fmaxf(M, red_m[w2][tt][qq]);
            float L = 0.f;
#pragma unroll
            for (int w2 = 0; w2 < 4; ++w2)
                L += red_l[w2][tt][qq] * exp2_hw(red_m[w2][tt][qq] - M);
            const size_t mlb = (((size_t)b * MC + mc) * NCHUNK + nc) * 64;
            pml[mlb + np]      = M;
            pml[mlb + 32 + np] = L;
        }
    }
}

// ---------------------------------------------------------------------------
// Kernel 3: combine MC partials -> y[32i][32n], then fused outconv+residual.
// grid = (NCHUNK, NB), block = 256.
// ---------------------------------------------------------------------------
__global__ __launch_bounds__(256) void combine_outconv(
    const float* __restrict__ pacc, const float* __restrict__ pml,
    const float* __restrict__ Ww, const float* __restrict__ Wb,
    const float* __restrict__ x, float* __restrict__ out)
{
    __shared__ float sml[MC * 64];        // [mc][ M(32) | L(32) ]
    __shared__ float ysh[32 * 33];        // y[i][n], pitch 33
    __shared__ float WwT[32 * 65];        // WwT[i][o], pitch 65
    __shared__ float swb[64];

    const int b  = blockIdx.y;
    const int nc = blockIdx.x;
    const int tid = threadIdx.x;
    const int n  = tid & 31;
    const int ig = tid >> 5;

    // stage pml (512 floats), WwT (2048), Wb (64)
    {
        int k0 = tid, k1 = tid + 256;
        sml[k0] = pml[(((size_t)b * MC + (k0 >> 6)) * NCHUNK + nc) * 64 + (k0 & 63)];
        sml[k1] = pml[(((size_t)b * MC + (k1 >> 6)) * NCHUNK + nc) * 64 + (k1 & 63)];
#pragma unroll
        for (int e = tid; e < 2048; e += 256)
            WwT[(e & 31) * 65 + (e >> 5)] = Ww[e];
        if (tid < 64) swb[tid] = Wb[tid];
    }

    // residual loads issued early (hide under combine)
    float xr[8];
    const float* xp = x + ((size_t)b * CIN + ig * 8) * BN + nc * 32 + n;
#pragma unroll
    for (int oo = 0; oo < 8; ++oo) xr[oo] = xp[(size_t)oo * BN];

    __syncthreads();

    // softmax global factors for this n, then combine partial accs
    {
        float M = sml[0 * 64 + n];
#pragma unroll
        for (int mc2 = 1; mc2 < MC; ++mc2) M = fmaxf(M, sml[mc2 * 64 + n]);
        float L = 0.f;
        float emc[MC];
#pragma unroll
        for (int mc2 = 0; mc2 < MC; ++mc2) {
            emc[mc2] = exp2_hw(sml[mc2 * 64 + n] - M);
            L += sml[mc2 * 64 + 32 + n] * emc[mc2];
        }
        float inv = 1.0f / L;
#pragma unroll
        for (int mc2 = 0; mc2 < MC; ++mc2) emc[mc2] *= inv;

        const size_t pb0 = (((size_t)b * MC) * NCHUNK + nc) * 1024;
#pragma unroll
        for (int ii = 0; ii < 4; ++ii) {
            const int i = ig * 4 + ii;
            float y = 0.f;
#pragma unroll
            for (int mc2 = 0; mc2 < MC; ++mc2)
                y += pacc[pb0 + (size_t)mc2 * NCHUNK * 1024 + (size_t)i * 32 + n]
                     * emc[mc2];
            ysh[i * 33 + n] = y;
        }
    }
    __syncthreads();

    // outconv: thread handles 8 output channels o = ig*8+oo at column n
    {
        float acc[8];
#pragma unroll
        for (int oo = 0; oo < 8; ++oo) acc[oo] = swb[ig * 8 + oo];
#pragma unroll
        for (int i = 0; i < 32; ++i) {
            float yv = ysh[i * 33 + n];
#pragma unroll
            for (int oo = 0; oo < 8; ++oo)
                acc[oo] += WwT[i * 65 + ig * 8 + oo] * yv;
        }
        float* op = out + ((size_t)b * CIN + ig * 8) * BN + nc * 32 + n;
#pragma unroll
        for (int oo = 0; oo < 8; ++oo) op[(size_t)oo * BN] = acc[oo] + xr[oo];
    }
}

// ---------------------------------------------------------------------------
extern "C" void kernel_launch(void* const* d_in, const int* in_sizes, int n_in,
                              void* d_out, int out_size, void* d_ws, size_t ws_size,
                              hipStream_t stream)
{
    const float* x    = (const float*)d_in[0];
    const float* g_w  = (const float*)d_in[1];
    const float* g_b  = (const float*)d_in[2];
    const float* th_w = (const float*)d_in[3];
    const float* th_b = (const float*)d_in[4];
    const float* ph_w = (const float*)d_in[5];
    const float* ph_b = (const float*)d_in[6];
    const float* W_w  = (const float*)d_in[7];
    const float* W_b  = (const float*)d_in[8];
    float* out = (float*)d_out;

    char* ws = (char*)d_ws;
    unsigned short* qT = (unsigned short*)(ws);                  // 1,179,648 B
    unsigned short* kT = (unsigned short*)(ws + 1179648);        // 1,179,648 B
    unsigned short* vv = (unsigned short*)(ws + 2359296);        // 1,179,648 B
    float* pacc = (float*)(ws + 3538944);    // 2*8*288*1024*4 = 18,874,368 B
    float* pml  = (float*)(ws + 22413312);   // 2*8*288*64*4   =  1,179,648 B

    dim3 g1(BN / 64, 12, NB);
    qkv_kernel<<<g1, 64, 0, stream>>>(x, g_w, g_b, th_w, th_b, ph_w, ph_b,
                                      qT, kT, vv);
    dim3 g2(NCHUNK, MC, NB);
    attn_partial<<<g2, 256, 0, stream>>>(qT, kT, vv, pacc, pml);
    dim3 g3(NCHUNK, NB);
    combine_outconv<<<g3, 256, 0, stream>>>(pacc, pml, W_w, W_b, x, out);
}